// Round 1
// baseline (375.004 us; speedup 1.0000x reference)
//
#include <hip/hip_runtime.h>

#define NB 4
#define NPRI 3106
#define NC 21
#define NCLS 20
#define KMAX 200
#define NMAX 1024   /* candidate capacity per (image,class) */
#define WMAX 16     /* NMAX/64 */
#define TMAX (WMAX*(WMAX+1)/2)   /* 136 triangular 64x64 tiles */
#define TBLK (TMAX/4)            /* 34 tile blocks per (image,class) */
#define MIN_SC 0.05f
#define MAX_OV 0.45f

/* ---- workspace layout (float-element offsets; u64 arrays at even offsets) ----
   R0 fusion: softmax is computed in-register inside det_prep, so the F_PROBS
   region never holds probs anymore; its first NB*NCLS ints are reused as the
   per-(b,c) tile-done counters for the mbuild->finish in-kernel handoff. */
#define F_PROBS 0                                  /* repurposed, see F_TDONE    */
#define F_TDONE F_PROBS                            /* NB*NCLS ints               */
#define F_KEYS  (F_PROBS + NB*NCLS*NPRI)           /* NB*NCLS*NMAX u64 (sorted)  */
#define F_BOXES (F_KEYS + NB*NCLS*NMAX*2)          /* NB*NCLS*NMAX float4        */
#define F_AREAS (F_BOXES + NB*NCLS*NMAX*4)         /* NB*NCLS*NMAX floats        */
#define F_NCAND (F_AREAS + NB*NCLS*NMAX)           /* NB*NCLS ints (pad to 128)  */
#define F_M     (F_NCAND + 128)                    /* NB*NCLS*WMAX*NMAX u64      */
#define F_POOL  (F_M + NB*NCLS*WMAX*NMAX*2)        /* NB*NCLS*KMAX u64           */
#define F_CNT   (F_POOL + NB*NCLS*KMAX*2)          /* NB*NCLS ints               */
#define F_DONE  (F_CNT + NB*NCLS)                  /* NB ints (per-image done)   */

/* ---- output layout (floats) ---- */
#define OUT_BOXES  0
#define OUT_LABELS (NB*KMAX*4)
#define OUT_SCORES (OUT_LABELS + NB*KMAX)
#define OUT_COUNTS (OUT_SCORES + NB*KMAX)

__device__ __forceinline__ float bcast(float v, int l) {
    return __uint_as_float(__builtin_amdgcn_readlane(__float_as_uint(v), l));
}

__device__ __forceinline__ void decode_box(const float* __restrict__ locs,
                                           const float* __restrict__ priors,
                                           int b, int pi,
                                           float& x1, float& y1, float& x2, float& y2) {
    const float* l  = locs + ((size_t)b * NPRI + pi) * 4;
    const float* pr = priors + (size_t)pi * 4;
    float pcx = pr[0], pcy = pr[1], pw = pr[2], ph = pr[3];
    /* reference op order: (l*pw)/10 + pcx ; exp(l/5)*pw ; cx -/+ w/2 */
    float cx = l[0] * pw / 10.0f + pcx;
    float cy = l[1] * ph / 10.0f + pcy;
    float w  = expf(l[2] / 5.0f) * pw;
    float h  = expf(l[3] / 5.0f) * ph;
    x1 = cx - w / 2.0f;  y1 = cy - h / 2.0f;
    x2 = cx + w / 2.0f;  y2 = cy + h / 2.0f;
}

/* K1 (R0 fused): per (image,class) block computes its class's softmax probs
   in-register (op-for-op identical to the old det_softmax: same fmax chain,
   same sequential exp/sum order, same e/sum), compacts > 0.05, bitonic-sorts,
   decodes. 512 threads halve the bitonic pass count vs the old 256.
   Also zero-inits the tile-done / image-done counters for K2 (stream order
   guarantees visibility before K2 starts). */
__global__ __launch_bounds__(512)
void det_prep(const float* __restrict__ scores, const float* __restrict__ locs,
              const float* __restrict__ priors, float* __restrict__ ws) {
    const int bc  = blockIdx.x;
    const int b   = bc / NCLS;
    const int c   = bc - b * NCLS;        /* 0..19 ; score column = c+1 */
    const int tid = threadIdx.x;

    __shared__ float rows[512 * NC];            /* 43008 B */
    __shared__ unsigned long long keys[NMAX];   /* 8192 B  */
    __shared__ int n_sh;
    if (tid == 0) {
        n_sh = 0;
        ((int*)(ws + F_TDONE))[bc] = 0;
        if (c == 0) ((int*)(ws + F_DONE))[b] = 0;
    }
    __syncthreads();

    /* softmax + threshold + compaction, chunked LDS staging (coalesced) */
    const float* sbase = scores + (size_t)b * NPRI * NC;
    for (int base = 0; base < NPRI; base += 512) {
        int cnt = NPRI - base; if (cnt > 512) cnt = 512;
        const int tot = cnt * NC;
        for (int i = tid; i < tot; i += 512)
            rows[i] = sbase[(size_t)base * NC + i];
        __syncthreads();
        if (tid < cnt) {
            const float* s = rows + tid * NC;   /* stride 21: bank-conflict-free */
            float m = -1e30f;
            #pragma unroll
            for (int k = 0; k < NC; ++k) m = fmaxf(m, s[k]);
            float sum = 0.0f, ec = 0.0f;
            #pragma unroll
            for (int k = 0; k < NC; ++k) {
                float e = expf(s[k] - m);
                sum += e;
                if (k == c + 1) ec = e;
            }
            float val = ec / sum;               /* == old e[c]/sum bitwise */
            if (val > MIN_SC) {
                int idx = atomicAdd(&n_sh, 1);
                if (idx < NMAX) {
                    unsigned int sb = __float_as_uint(val);
                    keys[idx] = ((unsigned long long)(~sb) << 32)
                              | (unsigned int)(base + tid);
                }
            }
        }
        __syncthreads();
    }
    int n = n_sh; if (n > NMAX) n = NMAX;

    /* bitonic sort (proven structure, 512-thread stride) */
    int npow = 1; while (npow < n) npow <<= 1;
    for (int i = n + tid; i < npow; i += 512) keys[i] = ~0ull;
    for (int k = 2; k <= npow; k <<= 1) {
        for (int j = k >> 1; j > 0; j >>= 1) {
            __syncthreads();
            for (int i = tid; i < npow; i += 512) {
                int ixj = i ^ j;
                if (ixj > i) {
                    unsigned long long a = keys[i], d = keys[ixj];
                    bool up = ((i & k) == 0);
                    if ((a > d) == up) { keys[i] = d; keys[ixj] = a; }
                }
            }
        }
    }
    __syncthreads();

    if (tid == 0) ((int*)(ws + F_NCAND))[bc] = n;
    unsigned long long* gk = (unsigned long long*)(ws + F_KEYS) + (size_t)bc * NMAX;
    float4* gb = (float4*)(ws + F_BOXES) + (size_t)bc * NMAX;
    float*  ga = ws + F_AREAS + (size_t)bc * NMAX;
    for (int i = tid; i < n; i += 512) {
        unsigned long long k = keys[i];
        gk[i] = k;
        int pi = (int)(k & 0xFFFFFFFFull);
        float x1, y1, x2, y2;
        decode_box(locs, priors, b, pi, x1, y1, x2, y2);
        gb[i] = make_float4(x1, y1, x2, y2);
        ga[i] = (x2 - x1) * (y2 - y1);
    }
}

/* K2 (R0 fused): grid (TBLK+1, NB*NCLS).
   blockIdx.x < TBLK : tile role — the round-11 proven mbuild 64x64 tile code,
     byte-identical inner loop (issue-bound at ~75% VALUBusy; do not touch).
     Each tile block release-increments tdone[bc] when its M words are visible.
   blockIdx.x == TBLK: finish role — acquire-spins for tdone[bc]==TBLK, then
     runs the proven resolve + pool + per-image merge + topk verbatim.
     Dispatch order places each bc's finish block right after its own 34 tile
     blocks, so resolve overlaps the remaining bcs' tile compute.
   Correctness does NOT depend on dispatch order: tile blocks never wait, and
   at most 80 spinner blocks << resident capacity, so progress is guaranteed.
   __launch_bounds__(256,4) caps VGPR at 128 so the tile role keeps >=16
   waves/CU (tile code itself needs only 16 VGPRs). */
__global__ __launch_bounds__(256, 4)
void det_build_finish(const float* __restrict__ locs, const float* __restrict__ priors,
                      float* __restrict__ ws, float* __restrict__ out) {
    const int bc = blockIdx.y;
    int* tdone = (int*)(ws + F_TDONE);

    if (blockIdx.x < TBLK) {
        /* ---------------- tile role (verbatim K2 v3) ---------------- */
        const int t    = blockIdx.x * 4 + (threadIdx.x >> 6);
        const int lane = threadIdx.x & 63;
        int tj = 0;
        while ((tj + 1) * (tj + 2) / 2 <= t) ++tj;   /* wave-uniform decode */
        const int w = t - tj * (tj + 1) / 2;          /* w <= tj */
        const int n = ((const int*)(ws + F_NCAND))[bc];
        const int bi0 = w * 64, bj0 = tj * 64;
        if (bj0 < n) {
            const float4* bx = (const float4*)(ws + F_BOXES) + (size_t)bc * NMAX;
            const float*  ar = ws + F_AREAS + (size_t)bc * NMAX;
            const float4 bi = bx[bi0 + lane];
            const float  ai = ar[bi0 + lane];
            const float4 bj = bx[bj0 + lane];
            const float  aj = ar[bj0 + lane];
            const unsigned long long vm =
                (n - bi0 >= 64) ? ~0ull : ((1ull << (n - bi0)) - 1ull);
            const bool diag = (w == tj);
            unsigned long long myword = 0ull;

            #pragma unroll
            for (int jj = 0; jj < 64; jj += 2) {
                float ax1 = bcast(bj.x, jj),     ay1 = bcast(bj.y, jj);
                float ax2 = bcast(bj.z, jj),     ay2 = bcast(bj.w, jj);
                float aau = bcast(aj, jj);
                float bx1 = bcast(bj.x, jj + 1), by1 = bcast(bj.y, jj + 1);
                float bx2 = bcast(bj.z, jj + 1), by2 = bcast(bj.w, jj + 1);
                float bau = bcast(aj, jj + 1);

                float alx = fmaxf(bi.x, ax1), aly = fmaxf(bi.y, ay1);
                float arx = fminf(bi.z, ax2), ary = fminf(bi.w, ay2);
                float blx = fmaxf(bi.x, bx1), bly = fmaxf(bi.y, by1);
                float brx = fminf(bi.z, bx2), bry = fminf(bi.w, by2);
                float adx = fmaxf(arx - alx, 0.0f), ady = fmaxf(ary - aly, 0.0f);
                float bdx = fmaxf(brx - blx, 0.0f), bdy = fmaxf(bry - bly, 0.0f);
                float ain = adx * ady;
                float bin = bdx * bdy;
                float au  = ai + aau - ain;
                float bu  = ai + bau - bin;
                float at  = MAX_OV * au;
                float bt  = MAX_OV * bu;
                bool akeep = ain > at;
                bool bkeep = bin > bt;
                bool anear = fabsf(ain - at) <= at * 6e-7f;
                bool bnear = fabsf(bin - bt) <= bt * 6e-7f;
                if (__ballot(anear || bnear)) {       /* rare: exact ref-order divide */
                    float aio = ain / au;
                    float bio = bin / bu;
                    akeep = anear ? (aio > MAX_OV) : akeep;
                    bkeep = bnear ? (bio > MAX_OV) : bkeep;
                }
                unsigned long long abits = __ballot(akeep) & vm;
                unsigned long long bbits = __ballot(bkeep) & vm;
                if (diag) {
                    abits &= (1ull << jj) - 1ull;      /* i < j on diagonal tile */
                    bbits &= (1ull << (jj + 1)) - 1ull;
                }
                if (lane == jj)     myword = abits;
                if (lane == jj + 1) myword = bbits;
            }
            if (bj0 + lane < n)
                ((unsigned long long*)(ws + F_M))
                    [((size_t)bc * WMAX + w) * NMAX + bj0 + lane] = myword;
        }
        /* release: all 4 waves' M stores visible, then count this block */
        __threadfence();
        __syncthreads();
        if (threadIdx.x == 0)
            __hip_atomic_fetch_add(tdone + bc, 1, __ATOMIC_RELEASE,
                                   __HIP_MEMORY_SCOPE_AGENT);
        return;
    }

    /* ---------------- finish role (verbatim round-11 det_finish) ---------------- */
    const int b    = bc / NCLS;
    const int c    = bc - b * NCLS;       /* 0..19 */
    const int cls  = c + 1;
    const int tid  = threadIdx.x;
    int* done_i = (int*)(ws + F_DONE);

    /* acquire: wait for this bc's 34 tile blocks */
    if (tid == 0) {
        int it = 0;
        while (__hip_atomic_load(tdone + bc, __ATOMIC_ACQUIRE,
                                 __HIP_MEMORY_SCOPE_AGENT) < TBLK
               && it < (1 << 20)) ++it;
    }
    __syncthreads();

    if (tid < 64) {
        const int lane = tid;
        const int n    = ((const int*)(ws + F_NCAND))[bc];
        const unsigned long long* Mb =
            (const unsigned long long*)(ws + F_M) + (size_t)bc * WMAX * NMAX;

        unsigned long long kw[WMAX];
        #pragma unroll
        for (int w = 0; w < WMAX; ++w) kw[w] = 0ull;

        const unsigned long long lmask = (1ull << lane) - 1ull;
        #pragma unroll
        for (int w = 0; w < WMAX; ++w) {
            if (w * 64 < n) {
                int cc = w * 64 + lane;
                bool valid = cc < n;
                unsigned long long pre = 0ull;
                #pragma unroll
                for (int v = 0; v < WMAX; ++v)
                    if (v < w) pre |= Mb[(size_t)v * NMAX + cc] & kw[v];
                unsigned long long dg = Mb[(size_t)w * NMAX + cc] & lmask;
                bool sup0 = (pre != 0ull);
                unsigned long long K = __ballot(valid && !sup0);
                for (int it = 0; it < 64; ++it) {
                    bool sup = sup0 || ((dg & K) != 0ull);
                    unsigned long long Kn = __ballot(valid && !sup);
                    if (Kn == K) break;
                    K = Kn;
                }
                kw[w] = K;
            }
        }

        int pref[WMAX + 1];
        pref[0] = 0;
        #pragma unroll
        for (int w = 0; w < WMAX; ++w) pref[w + 1] = pref[w] + __popcll(kw[w]);
        if (lane == 0) ((int*)(ws + F_CNT))[bc] = pref[WMAX];

        const unsigned long long* gk =
            (const unsigned long long*)(ws + F_KEYS) + (size_t)bc * NMAX;
        unsigned long long* pool =
            (unsigned long long*)(ws + F_POOL) + (size_t)bc * KMAX;
        const unsigned long long ctag = (unsigned long long)(cls << 12);
        #pragma unroll
        for (int w = 0; w < WMAX; ++w) {
            unsigned long long kwv = kw[w];
            int cc = w * 64 + lane;
            if (cc < n && ((kwv >> lane) & 1ull)) {
                int pos = pref[w] + __popcll(kwv & lmask);
                if (pos < KMAX) pool[pos] = gk[cc] | ctag;
            }
        }
    }

    /* zero image b's output slice, partitioned over its 20 blocks */
    {
        int idx = c * 256 + tid;
        if (idx < KMAX * 4) {
            out[OUT_BOXES + (size_t)b * KMAX * 4 + idx] = 0.0f;
        } else if (idx < KMAX * 4 + KMAX) {
            out[OUT_LABELS + b * KMAX + (idx - KMAX * 4)] = 0.0f;
        } else if (idx < KMAX * 4 + 2 * KMAX) {
            out[OUT_SCORES + b * KMAX + (idx - KMAX * 4 - KMAX)] = 0.0f;
        }
    }

    __threadfence();
    __syncthreads();
    if (tid == 0)
        __hip_atomic_fetch_add(done_i + b, 1, __ATOMIC_RELEASE,
                               __HIP_MEMORY_SCOPE_AGENT);

    if (tid == 0) {
        int it = 0;
        while (__hip_atomic_load(done_i + b, __ATOMIC_ACQUIRE,
                                 __HIP_MEMORY_SCOPE_AGENT) < NCLS
               && it < (1 << 20)) ++it;
    }
    __syncthreads();

    __shared__ unsigned long long lpool[NCLS * KMAX];  /* 32 KB */
    __shared__ int cnts[NCLS];

    const int* cnt = (const int*)(ws + F_CNT);
    if (tid < NCLS) cnts[tid] = cnt[b * NCLS + tid];
    __syncthreads();

    const unsigned long long* pool =
        (const unsigned long long*)(ws + F_POOL) + (size_t)b * NCLS * KMAX;
    for (int i = tid; i < NCLS * KMAX; i += 256) {
        int c2 = i / KMAX, r = i - c2 * KMAX;
        int mc2 = cnts[c2] < KMAX ? cnts[c2] : KMAX;
        lpool[i] = (r < mc2) ? pool[i] : ~0ull;
    }
    __syncthreads();

    if (c == 0 && tid == 0) {
        int tot = 0;
        for (int c2 = 0; c2 < NCLS; ++c2) tot += cnts[c2];
        int count = tot < KMAX ? tot : KMAX;
        if (tot == 0) {
            float* ob = out + OUT_BOXES + (size_t)b * KMAX * 4;
            ob[0] = 0.0f; ob[1] = 0.0f; ob[2] = 1.0f; ob[3] = 1.0f;
            count = 1;
        }
        out[OUT_COUNTS + b] = (float)count;
    }

    const int mc = cnts[c] < KMAX ? cnts[c] : KMAX;
    if (tid < mc) {
        unsigned long long key = lpool[c * KMAX + tid];
        int rank = 0;
        #pragma unroll
        for (int c2 = 0; c2 < NCLS; ++c2) {
            int lo = 0, hi = KMAX;
            #pragma unroll
            for (int s = 0; s < 8; ++s) {          /* ceil(log2(201)) = 8 */
                int mid = (lo + hi) >> 1;
                int midc = mid < KMAX ? mid : KMAX - 1;
                unsigned long long v = lpool[c2 * KMAX + midc];
                bool lt = (lo < hi) && (v < key);
                lo = lt ? mid + 1 : lo;
                hi = lt ? hi : mid;
            }
            rank += lo;
        }
        if (rank < KMAX) {
            unsigned int lo32 = (unsigned int)key;
            int pi  = lo32 & 0xFFF;
            int lab = (lo32 >> 12) & 0x1F;
            float sc = __uint_as_float(~(unsigned int)(key >> 32));
            float x1, y1, x2, y2;
            decode_box(locs, priors, b, pi, x1, y1, x2, y2);
            float* ob = out + OUT_BOXES + ((size_t)b * KMAX + rank) * 4;
            ob[0] = x1; ob[1] = y1; ob[2] = x2; ob[3] = y2;
            out[OUT_LABELS + b * KMAX + rank] = (float)lab;
            out[OUT_SCORES + b * KMAX + rank] = sc;
        }
    }
}

extern "C" void kernel_launch(void* const* d_in, const int* in_sizes, int n_in,
                              void* d_out, int out_size, void* d_ws, size_t ws_size,
                              hipStream_t stream) {
    const float* locs   = (const float*)d_in[0];
    const float* scores = (const float*)d_in[1];
    const float* priors = (const float*)d_in[2];
    float* out = (float*)d_out;
    float* ws  = (float*)d_ws;

    det_prep<<<NB * NCLS, 512, 0, stream>>>(scores, locs, priors, ws);
    det_build_finish<<<dim3(TBLK + 1, NB * NCLS), 256, 0, stream>>>(locs, priors, ws, out);
}

// Round 2
// 176.308 us; speedup vs baseline: 2.1270x; 2.1270x over previous
//
#include <hip/hip_runtime.h>

#define NB 4
#define NPRI 3106
#define NC 21
#define NCLS 20
#define KMAX 200
#define NMAX 1024   /* candidate capacity per (image,class) */
#define WMAX 16     /* NMAX/64 */
#define TMAX (WMAX*(WMAX+1)/2)   /* 136 triangular 64x64 tiles */
#define MIN_SC 0.05f
#define MAX_OV 0.45f

/* ---- workspace layout (float-element offsets; u64 arrays at even offsets) ----
   F_PROBS region is unused since softmax is fused into det_prep (offsets kept
   identical to the proven baseline layout). */
#define F_PROBS 0                                  /* unused (layout anchor)     */
#define F_KEYS  (F_PROBS + NB*NCLS*NPRI)           /* NB*NCLS*NMAX u64 (sorted)  */
#define F_BOXES (F_KEYS + NB*NCLS*NMAX*2)          /* NB*NCLS*NMAX float4        */
#define F_AREAS (F_BOXES + NB*NCLS*NMAX*4)         /* NB*NCLS*NMAX floats        */
#define F_NCAND (F_AREAS + NB*NCLS*NMAX)           /* NB*NCLS ints (pad to 128)  */
#define F_M     (F_NCAND + 128)                    /* NB*NCLS*WMAX*NMAX u64      */
#define F_POOL  (F_M + NB*NCLS*WMAX*NMAX*2)        /* NB*NCLS*KMAX u64           */
#define F_CNT   (F_POOL + NB*NCLS*KMAX*2)          /* NB*NCLS ints               */
#define F_DONE  (F_CNT + NB*NCLS)                  /* NB ints (per-image done)   */

/* ---- output layout (floats) ---- */
#define OUT_BOXES  0
#define OUT_LABELS (NB*KMAX*4)
#define OUT_SCORES (OUT_LABELS + NB*KMAX)
#define OUT_COUNTS (OUT_SCORES + NB*KMAX)

__device__ __forceinline__ float bcast(float v, int l) {
    return __uint_as_float(__builtin_amdgcn_readlane(__float_as_uint(v), l));
}

__device__ __forceinline__ void decode_box(const float* __restrict__ locs,
                                           const float* __restrict__ priors,
                                           int b, int pi,
                                           float& x1, float& y1, float& x2, float& y2) {
    const float* l  = locs + ((size_t)b * NPRI + pi) * 4;
    const float* pr = priors + (size_t)pi * 4;
    float pcx = pr[0], pcy = pr[1], pw = pr[2], ph = pr[3];
    /* reference op order: (l*pw)/10 + pcx ; exp(l/5)*pw ; cx -/+ w/2 */
    float cx = l[0] * pw / 10.0f + pcx;
    float cy = l[1] * ph / 10.0f + pcy;
    float w  = expf(l[2] / 5.0f) * pw;
    float h  = expf(l[3] / 5.0f) * ph;
    x1 = cx - w / 2.0f;  y1 = cy - h / 2.0f;
    x2 = cx + w / 2.0f;  y2 = cy + h / 2.0f;
}

/* K1: per (image,class) block. Softmax fused in-block (op-for-op identical to
   the proven det_softmax: same fmax chain, same sequential exp/sum order, same
   e/sum division — verified bitwise by R1's absmax=0), threshold+compaction,
   1024-thread bitonic sort (one compare-swap per thread per pass), decode.
   No cross-block sync anywhere (R1's in-kernel agent-scope spin was a 6.5x
   regression: per-iteration L2 invalidates starved concurrent compute). */
__global__ __launch_bounds__(1024)
void det_prep(const float* __restrict__ scores, const float* __restrict__ locs,
              const float* __restrict__ priors, float* __restrict__ ws) {
    const int bc  = blockIdx.x;
    const int b   = bc / NCLS;
    const int c   = bc - b * NCLS;        /* 0..19 ; score column = c+1 */
    const int tid = threadIdx.x;

    __shared__ float rows[512 * NC];            /* 43008 B */
    __shared__ unsigned long long keys[NMAX];   /* 8192 B  */
    __shared__ int n_sh;
    if (tid == 0) n_sh = 0;
    __syncthreads();

    /* softmax + threshold + compaction, chunked LDS staging (coalesced) */
    const float* sbase = scores + (size_t)b * NPRI * NC;
    for (int base = 0; base < NPRI; base += 512) {
        int cnt = NPRI - base; if (cnt > 512) cnt = 512;
        const int tot = cnt * NC;
        for (int i = tid; i < tot; i += 1024)
            rows[i] = sbase[(size_t)base * NC + i];
        __syncthreads();
        if (tid < cnt) {
            const float* s = rows + tid * NC;   /* stride 21: bank-conflict-free */
            float m = -1e30f;
            #pragma unroll
            for (int k = 0; k < NC; ++k) m = fmaxf(m, s[k]);
            float sum = 0.0f, ec = 0.0f;
            #pragma unroll
            for (int k = 0; k < NC; ++k) {
                float e = expf(s[k] - m);
                sum += e;
                if (k == c + 1) ec = e;
            }
            float val = ec / sum;               /* bitwise == ref e[c]/sum */
            if (val > MIN_SC) {
                int idx = atomicAdd(&n_sh, 1);
                if (idx < NMAX) {
                    unsigned int sb = __float_as_uint(val);
                    keys[idx] = ((unsigned long long)(~sb) << 32)
                              | (unsigned int)(base + tid);
                }
            }
        }
        __syncthreads();
    }
    int n = n_sh; if (n > NMAX) n = NMAX;

    /* bitonic sort: npow <= 1024, one element per thread per pass */
    int npow = 1; while (npow < n) npow <<= 1;
    for (int i = n + tid; i < npow; i += 1024) keys[i] = ~0ull;
    for (int k = 2; k <= npow; k <<= 1) {
        for (int j = k >> 1; j > 0; j >>= 1) {
            __syncthreads();
            if (tid < npow) {
                int i = tid;
                int ixj = i ^ j;
                if (ixj > i) {
                    unsigned long long a = keys[i], d = keys[ixj];
                    bool up = ((i & k) == 0);
                    if ((a > d) == up) { keys[i] = d; keys[ixj] = a; }
                }
            }
        }
    }
    __syncthreads();

    if (tid == 0) ((int*)(ws + F_NCAND))[bc] = n;
    unsigned long long* gk = (unsigned long long*)(ws + F_KEYS) + (size_t)bc * NMAX;
    float4* gb = (float4*)(ws + F_BOXES) + (size_t)bc * NMAX;
    float*  ga = ws + F_AREAS + (size_t)bc * NMAX;
    for (int i = tid; i < n; i += 1024) {
        unsigned long long k = keys[i];
        gk[i] = k;
        int pi = (int)(k & 0xFFFFFFFFull);
        float x1, y1, x2, y2;
        decode_box(locs, priors, b, pi, x1, y1, x2, y2);
        gb[i] = make_float4(x1, y1, x2, y2);
        ga[i] = (x2 - x1) * (y2 - y1);
    }
}

/* K2 v3 (round-11 proven, 44.8 us, VERBATIM): 64x64 tile per wave, 136
   triangular tiles, TWO column-chains per unrolled step, divide-free with
   exact-div near band (bit-identical M). Issue-bound at ~75% VALUBusy; fatter
   tiles and 4-chain ILP both measured slower — do not revisit. */
__global__ __launch_bounds__(256)
void det_mbuild(float* __restrict__ ws) {
    if (blockIdx.x == 0 && blockIdx.y == 0 && threadIdx.x < NB)
        ((int*)(ws + F_DONE))[threadIdx.x] = 0;

    const int bc = blockIdx.y;
    const int t  = blockIdx.x * 4 + (threadIdx.x >> 6);
    if (t >= TMAX) return;
    const int lane = threadIdx.x & 63;
    int tj = 0;
    while ((tj + 1) * (tj + 2) / 2 <= t) ++tj;   /* wave-uniform decode */
    const int w = t - tj * (tj + 1) / 2;          /* w <= tj */
    const int n = ((const int*)(ws + F_NCAND))[bc];
    const int bi0 = w * 64, bj0 = tj * 64;
    if (bj0 >= n) return;

    const float4* bx = (const float4*)(ws + F_BOXES) + (size_t)bc * NMAX;
    const float*  ar = ws + F_AREAS + (size_t)bc * NMAX;
    const float4 bi = bx[bi0 + lane];
    const float  ai = ar[bi0 + lane];
    const float4 bj = bx[bj0 + lane];
    const float  aj = ar[bj0 + lane];
    const unsigned long long vm =
        (n - bi0 >= 64) ? ~0ull : ((1ull << (n - bi0)) - 1ull);
    const bool diag = (w == tj);
    unsigned long long myword = 0ull;

    #pragma unroll
    for (int jj = 0; jj < 64; jj += 2) {
        float ax1 = bcast(bj.x, jj),     ay1 = bcast(bj.y, jj);
        float ax2 = bcast(bj.z, jj),     ay2 = bcast(bj.w, jj);
        float aau = bcast(aj, jj);
        float bx1 = bcast(bj.x, jj + 1), by1 = bcast(bj.y, jj + 1);
        float bx2 = bcast(bj.z, jj + 1), by2 = bcast(bj.w, jj + 1);
        float bau = bcast(aj, jj + 1);

        float alx = fmaxf(bi.x, ax1), aly = fmaxf(bi.y, ay1);
        float arx = fminf(bi.z, ax2), ary = fminf(bi.w, ay2);
        float blx = fmaxf(bi.x, bx1), bly = fmaxf(bi.y, by1);
        float brx = fminf(bi.z, bx2), bry = fminf(bi.w, by2);
        float adx = fmaxf(arx - alx, 0.0f), ady = fmaxf(ary - aly, 0.0f);
        float bdx = fmaxf(brx - blx, 0.0f), bdy = fmaxf(bry - bly, 0.0f);
        float ain = adx * ady;
        float bin = bdx * bdy;
        float au  = ai + aau - ain;           /* union > 0 (areas positive) */
        float bu  = ai + bau - bin;
        float at  = MAX_OV * au;
        float bt  = MAX_OV * bu;
        bool akeep = ain > at;
        bool bkeep = bin > bt;
        bool anear = fabsf(ain - at) <= at * 6e-7f;
        bool bnear = fabsf(bin - bt) <= bt * 6e-7f;
        if (__ballot(anear || bnear)) {       /* rare: exact ref-order divide */
            float aio = ain / au;
            float bio = bin / bu;
            akeep = anear ? (aio > MAX_OV) : akeep;
            bkeep = bnear ? (bio > MAX_OV) : bkeep;
        }
        unsigned long long abits = __ballot(akeep) & vm;
        unsigned long long bbits = __ballot(bkeep) & vm;
        if (diag) {
            abits &= (1ull << jj) - 1ull;      /* i < j on diagonal tile */
            bbits &= (1ull << (jj + 1)) - 1ull;
        }
        if (lane == jj)     myword = abits;
        if (lane == jj + 1) myword = bbits;
    }
    if (bj0 + lane < n)
        ((unsigned long long*)(ws + F_M))
            [((size_t)bc * WMAX + w) * NMAX + bj0 + lane] = myword;
}

/* K3 (round-11 proven, VERBATIM): resolve (wave 0) + zero-fill + release/
   acquire via done[b], then per-class rank-select topk. Runs alone — its
   80-block done-spin has nothing to starve (proven benign). */
__global__ __launch_bounds__(256)
void det_finish(const float* __restrict__ locs, const float* __restrict__ priors,
                float* __restrict__ ws, float* __restrict__ out) {
    const int bc   = blockIdx.x;
    const int b    = bc / NCLS;
    const int c    = bc - b * NCLS;       /* 0..19 */
    const int cls  = c + 1;
    const int tid  = threadIdx.x;
    int* done_i = (int*)(ws + F_DONE);

    if (tid < 64) {
        const int lane = tid;
        const int n    = ((const int*)(ws + F_NCAND))[bc];
        const unsigned long long* Mb =
            (const unsigned long long*)(ws + F_M) + (size_t)bc * WMAX * NMAX;

        unsigned long long kw[WMAX];
        #pragma unroll
        for (int w = 0; w < WMAX; ++w) kw[w] = 0ull;

        const unsigned long long lmask = (1ull << lane) - 1ull;
        #pragma unroll
        for (int w = 0; w < WMAX; ++w) {
            if (w * 64 < n) {
                int cc = w * 64 + lane;
                bool valid = cc < n;
                unsigned long long pre = 0ull;
                #pragma unroll
                for (int v = 0; v < WMAX; ++v)
                    if (v < w) pre |= Mb[(size_t)v * NMAX + cc] & kw[v];
                unsigned long long dg = Mb[(size_t)w * NMAX + cc] & lmask;
                bool sup0 = (pre != 0ull);
                unsigned long long K = __ballot(valid && !sup0);
                for (int it = 0; it < 64; ++it) {
                    bool sup = sup0 || ((dg & K) != 0ull);
                    unsigned long long Kn = __ballot(valid && !sup);
                    if (Kn == K) break;
                    K = Kn;
                }
                kw[w] = K;
            }
        }

        int pref[WMAX + 1];
        pref[0] = 0;
        #pragma unroll
        for (int w = 0; w < WMAX; ++w) pref[w + 1] = pref[w] + __popcll(kw[w]);
        if (lane == 0) ((int*)(ws + F_CNT))[bc] = pref[WMAX];

        const unsigned long long* gk =
            (const unsigned long long*)(ws + F_KEYS) + (size_t)bc * NMAX;
        unsigned long long* pool =
            (unsigned long long*)(ws + F_POOL) + (size_t)bc * KMAX;
        const unsigned long long ctag = (unsigned long long)(cls << 12);
        #pragma unroll
        for (int w = 0; w < WMAX; ++w) {
            unsigned long long kwv = kw[w];
            int cc = w * 64 + lane;
            if (cc < n && ((kwv >> lane) & 1ull)) {
                int pos = pref[w] + __popcll(kwv & lmask);
                if (pos < KMAX) pool[pos] = gk[cc] | ctag;
            }
        }
    }

    /* zero image b's output slice, partitioned over its 20 blocks */
    {
        int idx = c * 256 + tid;
        if (idx < KMAX * 4) {
            out[OUT_BOXES + (size_t)b * KMAX * 4 + idx] = 0.0f;
        } else if (idx < KMAX * 4 + KMAX) {
            out[OUT_LABELS + b * KMAX + (idx - KMAX * 4)] = 0.0f;
        } else if (idx < KMAX * 4 + 2 * KMAX) {
            out[OUT_SCORES + b * KMAX + (idx - KMAX * 4 - KMAX)] = 0.0f;
        }
    }

    __threadfence();
    __syncthreads();
    if (tid == 0)
        __hip_atomic_fetch_add(done_i + b, 1, __ATOMIC_RELEASE,
                               __HIP_MEMORY_SCOPE_AGENT);

    if (tid == 0) {
        int it = 0;
        while (__hip_atomic_load(done_i + b, __ATOMIC_ACQUIRE,
                                 __HIP_MEMORY_SCOPE_AGENT) < NCLS
               && it < (1 << 20)) ++it;
    }
    __syncthreads();

    __shared__ unsigned long long lpool[NCLS * KMAX];  /* 32 KB */
    __shared__ int cnts[NCLS];

    const int* cnt = (const int*)(ws + F_CNT);
    if (tid < NCLS) cnts[tid] = cnt[b * NCLS + tid];
    __syncthreads();

    const unsigned long long* pool =
        (const unsigned long long*)(ws + F_POOL) + (size_t)b * NCLS * KMAX;
    for (int i = tid; i < NCLS * KMAX; i += 256) {
        int c2 = i / KMAX, r = i - c2 * KMAX;
        int mc2 = cnts[c2] < KMAX ? cnts[c2] : KMAX;
        lpool[i] = (r < mc2) ? pool[i] : ~0ull;
    }
    __syncthreads();

    if (c == 0 && tid == 0) {
        int tot = 0;
        for (int c2 = 0; c2 < NCLS; ++c2) tot += cnts[c2];
        int count = tot < KMAX ? tot : KMAX;
        if (tot == 0) {
            float* ob = out + OUT_BOXES + (size_t)b * KMAX * 4;
            ob[0] = 0.0f; ob[1] = 0.0f; ob[2] = 1.0f; ob[3] = 1.0f;
            count = 1;
        }
        out[OUT_COUNTS + b] = (float)count;
    }

    const int mc = cnts[c] < KMAX ? cnts[c] : KMAX;
    if (tid < mc) {
        unsigned long long key = lpool[c * KMAX + tid];
        int rank = 0;
        #pragma unroll
        for (int c2 = 0; c2 < NCLS; ++c2) {
            int lo = 0, hi = KMAX;
            #pragma unroll
            for (int s = 0; s < 8; ++s) {          /* ceil(log2(201)) = 8 */
                int mid = (lo + hi) >> 1;
                int midc = mid < KMAX ? mid : KMAX - 1;
                unsigned long long v = lpool[c2 * KMAX + midc];
                bool lt = (lo < hi) && (v < key);
                lo = lt ? mid + 1 : lo;
                hi = lt ? hi : mid;
            }
            rank += lo;
        }
        if (rank < KMAX) {
            unsigned int lo32 = (unsigned int)key;
            int pi  = lo32 & 0xFFF;
            int lab = (lo32 >> 12) & 0x1F;
            float sc = __uint_as_float(~(unsigned int)(key >> 32));
            float x1, y1, x2, y2;
            decode_box(locs, priors, b, pi, x1, y1, x2, y2);
            float* ob = out + OUT_BOXES + ((size_t)b * KMAX + rank) * 4;
            ob[0] = x1; ob[1] = y1; ob[2] = x2; ob[3] = y2;
            out[OUT_LABELS + b * KMAX + rank] = (float)lab;
            out[OUT_SCORES + b * KMAX + rank] = sc;
        }
    }
}

extern "C" void kernel_launch(void* const* d_in, const int* in_sizes, int n_in,
                              void* d_out, int out_size, void* d_ws, size_t ws_size,
                              hipStream_t stream) {
    const float* locs   = (const float*)d_in[0];
    const float* scores = (const float*)d_in[1];
    const float* priors = (const float*)d_in[2];
    float* out = (float*)d_out;
    float* ws  = (float*)d_ws;

    det_prep<<<NB * NCLS, 1024, 0, stream>>>(scores, locs, priors, ws);
    det_mbuild<<<dim3((TMAX + 3) / 4, NB * NCLS), 256, 0, stream>>>(ws);
    det_finish<<<NB * NCLS, 256, 0, stream>>>(locs, priors, ws, out);
}

// Round 3
// 156.392 us; speedup vs baseline: 2.3979x; 1.1273x over previous
//
#include <hip/hip_runtime.h>

#define NB 4
#define NPRI 3106
#define NC 21
#define NCLS 20
#define KMAX 200
#define NMAX 1024   /* candidate capacity per (image,class) */
#define WMAX 16     /* NMAX/64 */
#define TMAX (WMAX*(WMAX+1)/2)   /* 136 triangular 64x64 tiles */
#define MIN_SC 0.05f
#define MAX_OV 0.45f

/* ---- workspace layout (float-element offsets; u64 arrays at even offsets) ---- */
#define F_PROBS 0                                  /* unused (layout anchor)     */
#define F_KEYS  (F_PROBS + NB*NCLS*NPRI)           /* NB*NCLS*NMAX u64 (sorted)  */
#define F_BOXES (F_KEYS + NB*NCLS*NMAX*2)          /* NB*NCLS*NMAX float4        */
#define F_AREAS (F_BOXES + NB*NCLS*NMAX*4)         /* NB*NCLS*NMAX floats        */
#define F_NCAND (F_AREAS + NB*NCLS*NMAX)           /* NB*NCLS ints (pad to 128)  */
#define F_M     (F_NCAND + 128)                    /* NB*NCLS*WMAX*NMAX u64      */
#define F_POOL  (F_M + NB*NCLS*WMAX*NMAX*2)        /* NB*NCLS*KMAX u64           */
#define F_CNT   (F_POOL + NB*NCLS*KMAX*2)          /* NB*NCLS ints               */
#define F_DONE  (F_CNT + NB*NCLS)                  /* NB ints (per-image done)   */

/* ---- output layout (floats) ---- */
#define OUT_BOXES  0
#define OUT_LABELS (NB*KMAX*4)
#define OUT_SCORES (OUT_LABELS + NB*KMAX)
#define OUT_COUNTS (OUT_SCORES + NB*KMAX)

__device__ __forceinline__ float bcast(float v, int l) {
    return __uint_as_float(__builtin_amdgcn_readlane(__float_as_uint(v), l));
}

__device__ __forceinline__ void decode_box(const float* __restrict__ locs,
                                           const float* __restrict__ priors,
                                           int b, int pi,
                                           float& x1, float& y1, float& x2, float& y2) {
    const float* l  = locs + ((size_t)b * NPRI + pi) * 4;
    const float* pr = priors + (size_t)pi * 4;
    float pcx = pr[0], pcy = pr[1], pw = pr[2], ph = pr[3];
    /* reference op order: (l*pw)/10 + pcx ; exp(l/5)*pw ; cx -/+ w/2 */
    float cx = l[0] * pw / 10.0f + pcx;
    float cy = l[1] * ph / 10.0f + pcy;
    float w  = expf(l[2] / 5.0f) * pw;
    float h  = expf(l[3] / 5.0f) * ph;
    x1 = cx - w / 2.0f;  y1 = cy - h / 2.0f;
    x2 = cx + w / 2.0f;  y2 = cy + h / 2.0f;
}

__device__ __forceinline__ unsigned long long shfl_xor_u64(unsigned long long v, int m) {
    unsigned lo = (unsigned)v, hi = (unsigned)(v >> 32);
    lo = __shfl_xor(lo, m);
    hi = __shfl_xor(hi, m);
    return ((unsigned long long)hi << 32) | lo;
}

/* K1 (R3): per (image,class) block, barrier-diet rewrite of the R2 kernel
   (R2 measured 49-52 us at 6.4% VALUBusy = barrier/latency-bound: 14 staging
   barriers + ~55 barriered bitonic passes at 16 waves).
   - softmax phase: direct global reads (no LDS stage, no barriers); fmax/exp/
     sum chain op-for-op identical to the proven version -> bitwise probs.
   - sort phase: register-resident bitonic, one key per thread. Passes with
     j<=32 use __shfl_xor (no barrier); only j>=64 passes (10 of 55) go through
     LDS with 2 barriers each. Full 1024-network with ~0ull padding == the
     npow-network on the first n outputs (pads are the maximum key). */
__global__ __launch_bounds__(1024)
void det_prep(const float* __restrict__ scores, const float* __restrict__ locs,
              const float* __restrict__ priors, float* __restrict__ ws) {
    const int bc  = blockIdx.x;
    const int b   = bc / NCLS;
    const int c   = bc - b * NCLS;        /* 0..19 ; score column = c+1 */
    const int tid = threadIdx.x;

    __shared__ unsigned long long keys[NMAX];   /* 8192 B */
    __shared__ int n_sh;
    if (tid == 0) n_sh = 0;
    __syncthreads();

    /* softmax + threshold + compaction: ~3 rows/thread, direct global reads */
    const float* sbase = scores + (size_t)b * NPRI * NC;
    for (int r = tid; r < NPRI; r += 1024) {
        const float* s = sbase + (size_t)r * NC;
        float m = -1e30f;
        #pragma unroll
        for (int k = 0; k < NC; ++k) m = fmaxf(m, s[k]);
        float sum = 0.0f, ec = 0.0f;
        #pragma unroll
        for (int k = 0; k < NC; ++k) {
            float e = expf(s[k] - m);
            sum += e;
            if (k == c + 1) ec = e;
        }
        float val = ec / sum;               /* bitwise == ref e[c]/sum */
        if (val > MIN_SC) {
            int idx = atomicAdd(&n_sh, 1);
            if (idx < NMAX) {
                unsigned int sb = __float_as_uint(val);
                keys[idx] = ((unsigned long long)(~sb) << 32)
                          | (unsigned int)r;
            }
        }
    }
    __syncthreads();
    int n = n_sh; if (n > NMAX) n = NMAX;

    /* register-resident bitonic over the full 1024 network */
    unsigned long long mykey = (tid < n) ? keys[tid] : ~0ull;
    __syncthreads();   /* keys[] reused as the exchange buffer below */
    for (int k = 2; k <= NMAX; k <<= 1) {
        for (int j = k >> 1; j > 0; j >>= 1) {
            unsigned long long other;
            if (j >= 64) {
                keys[tid] = mykey;
                __syncthreads();
                other = keys[tid ^ j];
                __syncthreads();
            } else {
                other = shfl_xor_u64(mykey, j);
            }
            bool lower    = (tid & j) == 0;     /* I hold the smaller index */
            bool up       = (tid & k) == 0;
            bool take_min = (lower == up);
            bool swap     = take_min ? (other < mykey) : (other > mykey);
            mykey = swap ? other : mykey;
        }
    }

    if (tid == 0) ((int*)(ws + F_NCAND))[bc] = n;
    unsigned long long* gk = (unsigned long long*)(ws + F_KEYS) + (size_t)bc * NMAX;
    float4* gb = (float4*)(ws + F_BOXES) + (size_t)bc * NMAX;
    float*  ga = ws + F_AREAS + (size_t)bc * NMAX;
    if (tid < n) {
        gk[tid] = mykey;
        int pi = (int)(mykey & 0xFFFFFFFFull);
        float x1, y1, x2, y2;
        decode_box(locs, priors, b, pi, x1, y1, x2, y2);
        gb[tid] = make_float4(x1, y1, x2, y2);
        ga[tid] = (x2 - x1) * (y2 - y1);
    }
}

/* K2 v3 (round-11 proven, 44.8 us, VERBATIM): 64x64 tile per wave, 136
   triangular tiles, TWO column-chains per unrolled step, divide-free with
   exact-div near band (bit-identical M). Issue-bound at ~75% VALUBusy; fatter
   tiles and 4-chain ILP both measured slower — do not revisit. */
__global__ __launch_bounds__(256)
void det_mbuild(float* __restrict__ ws) {
    if (blockIdx.x == 0 && blockIdx.y == 0 && threadIdx.x < NB)
        ((int*)(ws + F_DONE))[threadIdx.x] = 0;

    const int bc = blockIdx.y;
    const int t  = blockIdx.x * 4 + (threadIdx.x >> 6);
    if (t >= TMAX) return;
    const int lane = threadIdx.x & 63;
    int tj = 0;
    while ((tj + 1) * (tj + 2) / 2 <= t) ++tj;   /* wave-uniform decode */
    const int w = t - tj * (tj + 1) / 2;          /* w <= tj */
    const int n = ((const int*)(ws + F_NCAND))[bc];
    const int bi0 = w * 64, bj0 = tj * 64;
    if (bj0 >= n) return;

    const float4* bx = (const float4*)(ws + F_BOXES) + (size_t)bc * NMAX;
    const float*  ar = ws + F_AREAS + (size_t)bc * NMAX;
    const float4 bi = bx[bi0 + lane];
    const float  ai = ar[bi0 + lane];
    const float4 bj = bx[bj0 + lane];
    const float  aj = ar[bj0 + lane];
    const unsigned long long vm =
        (n - bi0 >= 64) ? ~0ull : ((1ull << (n - bi0)) - 1ull);
    const bool diag = (w == tj);
    unsigned long long myword = 0ull;

    #pragma unroll
    for (int jj = 0; jj < 64; jj += 2) {
        float ax1 = bcast(bj.x, jj),     ay1 = bcast(bj.y, jj);
        float ax2 = bcast(bj.z, jj),     ay2 = bcast(bj.w, jj);
        float aau = bcast(aj, jj);
        float bx1 = bcast(bj.x, jj + 1), by1 = bcast(bj.y, jj + 1);
        float bx2 = bcast(bj.z, jj + 1), by2 = bcast(bj.w, jj + 1);
        float bau = bcast(aj, jj + 1);

        float alx = fmaxf(bi.x, ax1), aly = fmaxf(bi.y, ay1);
        float arx = fminf(bi.z, ax2), ary = fminf(bi.w, ay2);
        float blx = fmaxf(bi.x, bx1), bly = fmaxf(bi.y, by1);
        float brx = fminf(bi.z, bx2), bry = fminf(bi.w, by2);
        float adx = fmaxf(arx - alx, 0.0f), ady = fmaxf(ary - aly, 0.0f);
        float bdx = fmaxf(brx - blx, 0.0f), bdy = fmaxf(bry - bly, 0.0f);
        float ain = adx * ady;
        float bin = bdx * bdy;
        float au  = ai + aau - ain;           /* union > 0 (areas positive) */
        float bu  = ai + bau - bin;
        float at  = MAX_OV * au;
        float bt  = MAX_OV * bu;
        bool akeep = ain > at;
        bool bkeep = bin > bt;
        bool anear = fabsf(ain - at) <= at * 6e-7f;
        bool bnear = fabsf(bin - bt) <= bt * 6e-7f;
        if (__ballot(anear || bnear)) {       /* rare: exact ref-order divide */
            float aio = ain / au;
            float bio = bin / bu;
            akeep = anear ? (aio > MAX_OV) : akeep;
            bkeep = bnear ? (bio > MAX_OV) : bkeep;
        }
        unsigned long long abits = __ballot(akeep) & vm;
        unsigned long long bbits = __ballot(bkeep) & vm;
        if (diag) {
            abits &= (1ull << jj) - 1ull;      /* i < j on diagonal tile */
            bbits &= (1ull << (jj + 1)) - 1ull;
        }
        if (lane == jj)     myword = abits;
        if (lane == jj + 1) myword = bbits;
    }
    if (bj0 + lane < n)
        ((unsigned long long*)(ws + F_M))
            [((size_t)bc * WMAX + w) * NMAX + bj0 + lane] = myword;
}

/* K3 (round-11 proven, VERBATIM): resolve (wave 0) + zero-fill + release/
   acquire via done[b], then per-class rank-select topk. Runs alone — its
   80-block done-spin has nothing to starve (proven benign). */
__global__ __launch_bounds__(256)
void det_finish(const float* __restrict__ locs, const float* __restrict__ priors,
                float* __restrict__ ws, float* __restrict__ out) {
    const int bc   = blockIdx.x;
    const int b    = bc / NCLS;
    const int c    = bc - b * NCLS;       /* 0..19 */
    const int cls  = c + 1;
    const int tid  = threadIdx.x;
    int* done_i = (int*)(ws + F_DONE);

    if (tid < 64) {
        const int lane = tid;
        const int n    = ((const int*)(ws + F_NCAND))[bc];
        const unsigned long long* Mb =
            (const unsigned long long*)(ws + F_M) + (size_t)bc * WMAX * NMAX;

        unsigned long long kw[WMAX];
        #pragma unroll
        for (int w = 0; w < WMAX; ++w) kw[w] = 0ull;

        const unsigned long long lmask = (1ull << lane) - 1ull;
        #pragma unroll
        for (int w = 0; w < WMAX; ++w) {
            if (w * 64 < n) {
                int cc = w * 64 + lane;
                bool valid = cc < n;
                unsigned long long pre = 0ull;
                #pragma unroll
                for (int v = 0; v < WMAX; ++v)
                    if (v < w) pre |= Mb[(size_t)v * NMAX + cc] & kw[v];
                unsigned long long dg = Mb[(size_t)w * NMAX + cc] & lmask;
                bool sup0 = (pre != 0ull);
                unsigned long long K = __ballot(valid && !sup0);
                for (int it = 0; it < 64; ++it) {
                    bool sup = sup0 || ((dg & K) != 0ull);
                    unsigned long long Kn = __ballot(valid && !sup);
                    if (Kn == K) break;
                    K = Kn;
                }
                kw[w] = K;
            }
        }

        int pref[WMAX + 1];
        pref[0] = 0;
        #pragma unroll
        for (int w = 0; w < WMAX; ++w) pref[w + 1] = pref[w] + __popcll(kw[w]);
        if (lane == 0) ((int*)(ws + F_CNT))[bc] = pref[WMAX];

        const unsigned long long* gk =
            (const unsigned long long*)(ws + F_KEYS) + (size_t)bc * NMAX;
        unsigned long long* pool =
            (unsigned long long*)(ws + F_POOL) + (size_t)bc * KMAX;
        const unsigned long long ctag = (unsigned long long)(cls << 12);
        #pragma unroll
        for (int w = 0; w < WMAX; ++w) {
            unsigned long long kwv = kw[w];
            int cc = w * 64 + lane;
            if (cc < n && ((kwv >> lane) & 1ull)) {
                int pos = pref[w] + __popcll(kwv & lmask);
                if (pos < KMAX) pool[pos] = gk[cc] | ctag;
            }
        }
    }

    /* zero image b's output slice, partitioned over its 20 blocks */
    {
        int idx = c * 256 + tid;
        if (idx < KMAX * 4) {
            out[OUT_BOXES + (size_t)b * KMAX * 4 + idx] = 0.0f;
        } else if (idx < KMAX * 4 + KMAX) {
            out[OUT_LABELS + b * KMAX + (idx - KMAX * 4)] = 0.0f;
        } else if (idx < KMAX * 4 + 2 * KMAX) {
            out[OUT_SCORES + b * KMAX + (idx - KMAX * 4 - KMAX)] = 0.0f;
        }
    }

    __threadfence();
    __syncthreads();
    if (tid == 0)
        __hip_atomic_fetch_add(done_i + b, 1, __ATOMIC_RELEASE,
                               __HIP_MEMORY_SCOPE_AGENT);

    if (tid == 0) {
        int it = 0;
        while (__hip_atomic_load(done_i + b, __ATOMIC_ACQUIRE,
                                 __HIP_MEMORY_SCOPE_AGENT) < NCLS
               && it < (1 << 20)) ++it;
    }
    __syncthreads();

    __shared__ unsigned long long lpool[NCLS * KMAX];  /* 32 KB */
    __shared__ int cnts[NCLS];

    const int* cnt = (const int*)(ws + F_CNT);
    if (tid < NCLS) cnts[tid] = cnt[b * NCLS + tid];
    __syncthreads();

    const unsigned long long* pool =
        (const unsigned long long*)(ws + F_POOL) + (size_t)b * NCLS * KMAX;
    for (int i = tid; i < NCLS * KMAX; i += 256) {
        int c2 = i / KMAX, r = i - c2 * KMAX;
        int mc2 = cnts[c2] < KMAX ? cnts[c2] : KMAX;
        lpool[i] = (r < mc2) ? pool[i] : ~0ull;
    }
    __syncthreads();

    if (c == 0 && tid == 0) {
        int tot = 0;
        for (int c2 = 0; c2 < NCLS; ++c2) tot += cnts[c2];
        int count = tot < KMAX ? tot : KMAX;
        if (tot == 0) {
            float* ob = out + OUT_BOXES + (size_t)b * KMAX * 4;
            ob[0] = 0.0f; ob[1] = 0.0f; ob[2] = 1.0f; ob[3] = 1.0f;
            count = 1;
        }
        out[OUT_COUNTS + b] = (float)count;
    }

    const int mc = cnts[c] < KMAX ? cnts[c] : KMAX;
    if (tid < mc) {
        unsigned long long key = lpool[c * KMAX + tid];
        int rank = 0;
        #pragma unroll
        for (int c2 = 0; c2 < NCLS; ++c2) {
            int lo = 0, hi = KMAX;
            #pragma unroll
            for (int s = 0; s < 8; ++s) {          /* ceil(log2(201)) = 8 */
                int mid = (lo + hi) >> 1;
                int midc = mid < KMAX ? mid : KMAX - 1;
                unsigned long long v = lpool[c2 * KMAX + midc];
                bool lt = (lo < hi) && (v < key);
                lo = lt ? mid + 1 : lo;
                hi = lt ? hi : mid;
            }
            rank += lo;
        }
        if (rank < KMAX) {
            unsigned int lo32 = (unsigned int)key;
            int pi  = lo32 & 0xFFF;
            int lab = (lo32 >> 12) & 0x1F;
            float sc = __uint_as_float(~(unsigned int)(key >> 32));
            float x1, y1, x2, y2;
            decode_box(locs, priors, b, pi, x1, y1, x2, y2);
            float* ob = out + OUT_BOXES + ((size_t)b * KMAX + rank) * 4;
            ob[0] = x1; ob[1] = y1; ob[2] = x2; ob[3] = y2;
            out[OUT_LABELS + b * KMAX + rank] = (float)lab;
            out[OUT_SCORES + b * KMAX + rank] = sc;
        }
    }
}

extern "C" void kernel_launch(void* const* d_in, const int* in_sizes, int n_in,
                              void* d_out, int out_size, void* d_ws, size_t ws_size,
                              hipStream_t stream) {
    const float* locs   = (const float*)d_in[0];
    const float* scores = (const float*)d_in[1];
    const float* priors = (const float*)d_in[2];
    float* out = (float*)d_out;
    float* ws  = (float*)d_ws;

    det_prep<<<NB * NCLS, 1024, 0, stream>>>(scores, locs, priors, ws);
    det_mbuild<<<dim3((TMAX + 3) / 4, NB * NCLS), 256, 0, stream>>>(ws);
    det_finish<<<NB * NCLS, 256, 0, stream>>>(locs, priors, ws, out);
}

// Round 4
// 149.395 us; speedup vs baseline: 2.5102x; 1.0468x over previous
//
#include <hip/hip_runtime.h>

#define NB 4
#define NPRI 3106
#define NC 21
#define NCLS 20
#define KMAX 200
#define NMAX 1024   /* candidate capacity per (image,class) */
#define WMAX 16     /* NMAX/64 */
#define TMAX (WMAX*(WMAX+1)/2)   /* 136 triangular 64x64 tiles */
#define MIN_SC 0.05f
#define MAX_OV 0.45f

/* ---- workspace layout (float-element offsets; u64 arrays at even offsets) ---- */
#define F_PROBS 0                                  /* unused (layout anchor)     */
#define F_KEYS  (F_PROBS + NB*NCLS*NPRI)           /* NB*NCLS*NMAX u64 (sorted)  */
#define F_BOXES (F_KEYS + NB*NCLS*NMAX*2)          /* NB*NCLS*NMAX float4        */
#define F_AREAS (F_BOXES + NB*NCLS*NMAX*4)         /* NB*NCLS*NMAX floats        */
#define F_NCAND (F_AREAS + NB*NCLS*NMAX)           /* NB*NCLS ints (pad to 128)  */
#define F_M     (F_NCAND + 128)                    /* NB*NCLS*WMAX*NMAX u64      */
#define F_POOL  (F_M + NB*NCLS*WMAX*NMAX*2)        /* NB*NCLS*KMAX u64           */
#define F_CNT   (F_POOL + NB*NCLS*KMAX*2)          /* NB*NCLS ints               */
#define F_DONE  (F_CNT + NB*NCLS)                  /* NB ints (unused since R4)  */

/* ---- output layout (floats) ---- */
#define OUT_BOXES  0
#define OUT_LABELS (NB*KMAX*4)
#define OUT_SCORES (OUT_LABELS + NB*KMAX)
#define OUT_COUNTS (OUT_SCORES + NB*KMAX)

__device__ __forceinline__ float bcast(float v, int l) {
    return __uint_as_float(__builtin_amdgcn_readlane(__float_as_uint(v), l));
}

__device__ __forceinline__ void decode_box(const float* __restrict__ locs,
                                           const float* __restrict__ priors,
                                           int b, int pi,
                                           float& x1, float& y1, float& x2, float& y2) {
    const float* l  = locs + ((size_t)b * NPRI + pi) * 4;
    const float* pr = priors + (size_t)pi * 4;
    float pcx = pr[0], pcy = pr[1], pw = pr[2], ph = pr[3];
    /* reference op order: (l*pw)/10 + pcx ; exp(l/5)*pw ; cx -/+ w/2 */
    float cx = l[0] * pw / 10.0f + pcx;
    float cy = l[1] * ph / 10.0f + pcy;
    float w  = expf(l[2] / 5.0f) * pw;
    float h  = expf(l[3] / 5.0f) * ph;
    x1 = cx - w / 2.0f;  y1 = cy - h / 2.0f;
    x2 = cx + w / 2.0f;  y2 = cy + h / 2.0f;
}

__device__ __forceinline__ unsigned long long shfl_xor_u64(unsigned long long v, int m) {
    unsigned lo = (unsigned)v, hi = (unsigned)(v >> 32);
    lo = __shfl_xor(lo, m);
    hi = __shfl_xor(hi, m);
    return ((unsigned long long)hi << 32) | lo;
}

/* softmax chain — op-for-op identical to the proven kernel (bitwise probs) */
__device__ __forceinline__ void softmax_push(const float* __restrict__ v, int c,
                                             int r, unsigned long long* keys,
                                             int* n_sh) {
    float m = -1e30f;
    #pragma unroll
    for (int k = 0; k < NC; ++k) m = fmaxf(m, v[k]);
    float sum = 0.0f, ec = 0.0f;
    #pragma unroll
    for (int k = 0; k < NC; ++k) {
        float e = expf(v[k] - m);
        sum += e;
        if (k == c + 1) ec = e;
    }
    float val = ec / sum;               /* bitwise == ref e[c]/sum */
    if (val > MIN_SC) {
        int idx = atomicAdd(n_sh, 1);
        if (idx < NMAX) {
            unsigned int sb = __float_as_uint(val);
            keys[idx] = ((unsigned long long)(~sb) << 32) | (unsigned int)r;
        }
    }
}

/* K1 (R4): per (image,class) block. R3 measured prep load-latency-bound
   (only 80 blocks -> 1.25 waves/SIMD, 21 serial scalar loads/row). Fix:
   NPRI = 3*1024 + 34, so each thread owns rows {tid, tid+1024, tid+2048} —
   issue all 63 loads up-front into registers (static unroll, ~100 VGPR is
   free: occupancy is block-count-limited), then run the three bitwise-
   identical softmax chains. Tail rows 3072..3105 on threads 0..33.
   Sort: R3's register-resident bitonic (proven). */
__global__ __launch_bounds__(1024)
void det_prep(const float* __restrict__ scores, const float* __restrict__ locs,
              const float* __restrict__ priors, float* __restrict__ ws) {
    const int bc  = blockIdx.x;
    const int b   = bc / NCLS;
    const int c   = bc - b * NCLS;        /* 0..19 ; score column = c+1 */
    const int tid = threadIdx.x;

    __shared__ unsigned long long keys[NMAX];   /* 8192 B */
    __shared__ int n_sh;
    if (tid == 0) n_sh = 0;
    __syncthreads();

    const float* sbase = scores + (size_t)b * NPRI * NC;
    {
        float v0[NC], v1[NC], v2[NC];
        const float* s0 = sbase + (size_t)(tid)        * NC;
        const float* s1 = sbase + (size_t)(tid + 1024) * NC;
        const float* s2 = sbase + (size_t)(tid + 2048) * NC;
        #pragma unroll
        for (int k = 0; k < NC; ++k) { v0[k] = s0[k]; }
        #pragma unroll
        for (int k = 0; k < NC; ++k) { v1[k] = s1[k]; }
        #pragma unroll
        for (int k = 0; k < NC; ++k) { v2[k] = s2[k]; }
        softmax_push(v0, c, tid,        keys, &n_sh);
        softmax_push(v1, c, tid + 1024, keys, &n_sh);
        softmax_push(v2, c, tid + 2048, keys, &n_sh);
        if (tid < NPRI - 3072) {
            float v3[NC];
            const float* s3 = sbase + (size_t)(tid + 3072) * NC;
            #pragma unroll
            for (int k = 0; k < NC; ++k) { v3[k] = s3[k]; }
            softmax_push(v3, c, tid + 3072, keys, &n_sh);
        }
    }
    __syncthreads();
    int n = n_sh; if (n > NMAX) n = NMAX;

    /* register-resident bitonic over the full 1024 network (R3 proven):
       j<=32 passes via shfl_xor (no barrier), j>=64 via LDS. Full network
       with ~0ull padding == npow-network on the first n outputs. */
    unsigned long long mykey = (tid < n) ? keys[tid] : ~0ull;
    __syncthreads();   /* keys[] reused as the exchange buffer below */
    for (int k = 2; k <= NMAX; k <<= 1) {
        for (int j = k >> 1; j > 0; j >>= 1) {
            unsigned long long other;
            if (j >= 64) {
                keys[tid] = mykey;
                __syncthreads();
                other = keys[tid ^ j];
                __syncthreads();
            } else {
                other = shfl_xor_u64(mykey, j);
            }
            bool lower    = (tid & j) == 0;     /* I hold the smaller index */
            bool up       = (tid & k) == 0;
            bool take_min = (lower == up);
            bool swap     = take_min ? (other < mykey) : (other > mykey);
            mykey = swap ? other : mykey;
        }
    }

    if (tid == 0) ((int*)(ws + F_NCAND))[bc] = n;
    unsigned long long* gk = (unsigned long long*)(ws + F_KEYS) + (size_t)bc * NMAX;
    float4* gb = (float4*)(ws + F_BOXES) + (size_t)bc * NMAX;
    float*  ga = ws + F_AREAS + (size_t)bc * NMAX;
    if (tid < n) {
        gk[tid] = mykey;
        int pi = (int)(mykey & 0xFFFFFFFFull);
        float x1, y1, x2, y2;
        decode_box(locs, priors, b, pi, x1, y1, x2, y2);
        gb[tid] = make_float4(x1, y1, x2, y2);
        ga[tid] = (x2 - x1) * (y2 - y1);
    }
}

/* K2 v3 (round-11 proven, 44.8 us, VERBATIM): 64x64 tile per wave, 136
   triangular tiles, TWO column-chains per unrolled step, divide-free with
   exact-div near band (bit-identical M). Issue-bound at ~75% VALUBusy; fatter
   tiles and 4-chain ILP both measured slower — do not revisit. */
__global__ __launch_bounds__(256)
void det_mbuild(float* __restrict__ ws) {
    if (blockIdx.x == 0 && blockIdx.y == 0 && threadIdx.x < NB)
        ((int*)(ws + F_DONE))[threadIdx.x] = 0;

    const int bc = blockIdx.y;
    const int t  = blockIdx.x * 4 + (threadIdx.x >> 6);
    if (t >= TMAX) return;
    const int lane = threadIdx.x & 63;
    int tj = 0;
    while ((tj + 1) * (tj + 2) / 2 <= t) ++tj;   /* wave-uniform decode */
    const int w = t - tj * (tj + 1) / 2;          /* w <= tj */
    const int n = ((const int*)(ws + F_NCAND))[bc];
    const int bi0 = w * 64, bj0 = tj * 64;
    if (bj0 >= n) return;

    const float4* bx = (const float4*)(ws + F_BOXES) + (size_t)bc * NMAX;
    const float*  ar = ws + F_AREAS + (size_t)bc * NMAX;
    const float4 bi = bx[bi0 + lane];
    const float  ai = ar[bi0 + lane];
    const float4 bj = bx[bj0 + lane];
    const float  aj = ar[bj0 + lane];
    const unsigned long long vm =
        (n - bi0 >= 64) ? ~0ull : ((1ull << (n - bi0)) - 1ull);
    const bool diag = (w == tj);
    unsigned long long myword = 0ull;

    #pragma unroll
    for (int jj = 0; jj < 64; jj += 2) {
        float ax1 = bcast(bj.x, jj),     ay1 = bcast(bj.y, jj);
        float ax2 = bcast(bj.z, jj),     ay2 = bcast(bj.w, jj);
        float aau = bcast(aj, jj);
        float bx1 = bcast(bj.x, jj + 1), by1 = bcast(bj.y, jj + 1);
        float bx2 = bcast(bj.z, jj + 1), by2 = bcast(bj.w, jj + 1);
        float bau = bcast(aj, jj + 1);

        float alx = fmaxf(bi.x, ax1), aly = fmaxf(bi.y, ay1);
        float arx = fminf(bi.z, ax2), ary = fminf(bi.w, ay2);
        float blx = fmaxf(bi.x, bx1), bly = fmaxf(bi.y, by1);
        float brx = fminf(bi.z, bx2), bry = fminf(bi.w, by2);
        float adx = fmaxf(arx - alx, 0.0f), ady = fmaxf(ary - aly, 0.0f);
        float bdx = fmaxf(brx - blx, 0.0f), bdy = fmaxf(bry - bly, 0.0f);
        float ain = adx * ady;
        float bin = bdx * bdy;
        float au  = ai + aau - ain;           /* union > 0 (areas positive) */
        float bu  = ai + bau - bin;
        float at  = MAX_OV * au;
        float bt  = MAX_OV * bu;
        bool akeep = ain > at;
        bool bkeep = bin > bt;
        bool anear = fabsf(ain - at) <= at * 6e-7f;
        bool bnear = fabsf(bin - bt) <= bt * 6e-7f;
        if (__ballot(anear || bnear)) {       /* rare: exact ref-order divide */
            float aio = ain / au;
            float bio = bin / bu;
            akeep = anear ? (aio > MAX_OV) : akeep;
            bkeep = bnear ? (bio > MAX_OV) : bkeep;
        }
        unsigned long long abits = __ballot(akeep) & vm;
        unsigned long long bbits = __ballot(bkeep) & vm;
        if (diag) {
            abits &= (1ull << jj) - 1ull;      /* i < j on diagonal tile */
            bbits &= (1ull << (jj + 1)) - 1ull;
        }
        if (lane == jj)     myword = abits;
        if (lane == jj + 1) myword = bbits;
    }
    if (bj0 + lane < n)
        ((unsigned long long*)(ws + F_M))
            [((size_t)bc * WMAX + w) * NMAX + bj0 + lane] = myword;
}

/* K3a (R4): the pre-handshake half of the proven det_finish — resolve (wave 0)
   + pool/cnt writes + output zero-fill. NO atomics, NO spin: R1/R3 evidence
   says the agent-scope done[b] spin's per-poll L2 invalidates starve the
   concurrent resolves; the kernel boundary to K3b replaces it for ~2 us. */
__global__ __launch_bounds__(256)
void det_finishA(float* __restrict__ ws, float* __restrict__ out) {
    const int bc   = blockIdx.x;
    const int b    = bc / NCLS;
    const int c    = bc - b * NCLS;       /* 0..19 */
    const int cls  = c + 1;
    const int tid  = threadIdx.x;

    if (tid < 64) {
        const int lane = tid;
        const int n    = ((const int*)(ws + F_NCAND))[bc];
        const unsigned long long* Mb =
            (const unsigned long long*)(ws + F_M) + (size_t)bc * WMAX * NMAX;

        unsigned long long kw[WMAX];
        #pragma unroll
        for (int w = 0; w < WMAX; ++w) kw[w] = 0ull;

        const unsigned long long lmask = (1ull << lane) - 1ull;
        #pragma unroll
        for (int w = 0; w < WMAX; ++w) {
            if (w * 64 < n) {
                int cc = w * 64 + lane;
                bool valid = cc < n;
                unsigned long long pre = 0ull;
                #pragma unroll
                for (int v = 0; v < WMAX; ++v)
                    if (v < w) pre |= Mb[(size_t)v * NMAX + cc] & kw[v];
                unsigned long long dg = Mb[(size_t)w * NMAX + cc] & lmask;
                bool sup0 = (pre != 0ull);
                unsigned long long K = __ballot(valid && !sup0);
                for (int it = 0; it < 64; ++it) {
                    bool sup = sup0 || ((dg & K) != 0ull);
                    unsigned long long Kn = __ballot(valid && !sup);
                    if (Kn == K) break;
                    K = Kn;
                }
                kw[w] = K;
            }
        }

        int pref[WMAX + 1];
        pref[0] = 0;
        #pragma unroll
        for (int w = 0; w < WMAX; ++w) pref[w + 1] = pref[w] + __popcll(kw[w]);
        if (lane == 0) ((int*)(ws + F_CNT))[bc] = pref[WMAX];

        const unsigned long long* gk =
            (const unsigned long long*)(ws + F_KEYS) + (size_t)bc * NMAX;
        unsigned long long* pool =
            (unsigned long long*)(ws + F_POOL) + (size_t)bc * KMAX;
        const unsigned long long ctag = (unsigned long long)(cls << 12);
        #pragma unroll
        for (int w = 0; w < WMAX; ++w) {
            unsigned long long kwv = kw[w];
            int cc = w * 64 + lane;
            if (cc < n && ((kwv >> lane) & 1ull)) {
                int pos = pref[w] + __popcll(kwv & lmask);
                if (pos < KMAX) pool[pos] = gk[cc] | ctag;
            }
        }
    }

    /* zero image b's output slice, partitioned over its 20 blocks */
    {
        int idx = c * 256 + tid;
        if (idx < KMAX * 4) {
            out[OUT_BOXES + (size_t)b * KMAX * 4 + idx] = 0.0f;
        } else if (idx < KMAX * 4 + KMAX) {
            out[OUT_LABELS + b * KMAX + (idx - KMAX * 4)] = 0.0f;
        } else if (idx < KMAX * 4 + 2 * KMAX) {
            out[OUT_SCORES + b * KMAX + (idx - KMAX * 4 - KMAX)] = 0.0f;
        }
    }
}

/* K3b (R4): the post-handshake half of the proven det_finish, verbatim —
   per-(b,c) block stages the image's pool into LDS, computes count (c==0),
   rank-selects its class's keepers into the global top-K, decodes, writes. */
__global__ __launch_bounds__(256)
void det_finishB(const float* __restrict__ locs, const float* __restrict__ priors,
                 const float* __restrict__ ws, float* __restrict__ out) {
    const int bc   = blockIdx.x;
    const int b    = bc / NCLS;
    const int c    = bc - b * NCLS;       /* 0..19 */
    const int tid  = threadIdx.x;

    __shared__ unsigned long long lpool[NCLS * KMAX];  /* 32 KB */
    __shared__ int cnts[NCLS];

    const int* cnt = (const int*)(ws + F_CNT);
    if (tid < NCLS) cnts[tid] = cnt[b * NCLS + tid];
    __syncthreads();

    const unsigned long long* pool =
        (const unsigned long long*)(ws + F_POOL) + (size_t)b * NCLS * KMAX;
    for (int i = tid; i < NCLS * KMAX; i += 256) {
        int c2 = i / KMAX, r = i - c2 * KMAX;
        int mc2 = cnts[c2] < KMAX ? cnts[c2] : KMAX;
        lpool[i] = (r < mc2) ? pool[i] : ~0ull;
    }
    __syncthreads();

    if (c == 0 && tid == 0) {
        int tot = 0;
        for (int c2 = 0; c2 < NCLS; ++c2) tot += cnts[c2];
        int count = tot < KMAX ? tot : KMAX;
        if (tot == 0) {
            float* ob = out + OUT_BOXES + (size_t)b * KMAX * 4;
            ob[0] = 0.0f; ob[1] = 0.0f; ob[2] = 1.0f; ob[3] = 1.0f;
            count = 1;
        }
        out[OUT_COUNTS + b] = (float)count;
    }

    const int mc = cnts[c] < KMAX ? cnts[c] : KMAX;
    if (tid < mc) {
        unsigned long long key = lpool[c * KMAX + tid];
        int rank = 0;
        #pragma unroll
        for (int c2 = 0; c2 < NCLS; ++c2) {
            int lo = 0, hi = KMAX;
            #pragma unroll
            for (int s = 0; s < 8; ++s) {          /* ceil(log2(201)) = 8 */
                int mid = (lo + hi) >> 1;
                int midc = mid < KMAX ? mid : KMAX - 1;
                unsigned long long v = lpool[c2 * KMAX + midc];
                bool lt = (lo < hi) && (v < key);
                lo = lt ? mid + 1 : lo;
                hi = lt ? hi : mid;
            }
            rank += lo;
        }
        if (rank < KMAX) {
            unsigned int lo32 = (unsigned int)key;
            int pi  = lo32 & 0xFFF;
            int lab = (lo32 >> 12) & 0x1F;
            float sc = __uint_as_float(~(unsigned int)(key >> 32));
            float x1, y1, x2, y2;
            decode_box(locs, priors, b, pi, x1, y1, x2, y2);
            float* ob = out + OUT_BOXES + ((size_t)b * KMAX + rank) * 4;
            ob[0] = x1; ob[1] = y1; ob[2] = x2; ob[3] = y2;
            out[OUT_LABELS + b * KMAX + rank] = (float)lab;
            out[OUT_SCORES + b * KMAX + rank] = sc;
        }
    }
}

extern "C" void kernel_launch(void* const* d_in, const int* in_sizes, int n_in,
                              void* d_out, int out_size, void* d_ws, size_t ws_size,
                              hipStream_t stream) {
    const float* locs   = (const float*)d_in[0];
    const float* scores = (const float*)d_in[1];
    const float* priors = (const float*)d_in[2];
    float* out = (float*)d_out;
    float* ws  = (float*)d_ws;

    det_prep<<<NB * NCLS, 1024, 0, stream>>>(scores, locs, priors, ws);
    det_mbuild<<<dim3((TMAX + 3) / 4, NB * NCLS), 256, 0, stream>>>(ws);
    det_finishA<<<NB * NCLS, 256, 0, stream>>>(ws, out);
    det_finishB<<<NB * NCLS, 256, 0, stream>>>(locs, priors, ws, out);
}